// Round 1
// baseline (678.936 us; speedup 1.0000x reference)
//
#include <hip/hip_runtime.h>

// Per-pixel diagonal RNN, fp32 in/out.
// h_t = leaky_relu(W_ih*x_t + W_hh*h_{t-1} + b_hh), T=50, 2M independent pixels.
// Memory-bound target: ~864 MB traffic -> ~137 us roofline at 6.3 TB/s achievable.
//
// R1 theory: previous kernel (698 us, ~1.2 TB/s) is latency-bound, not BW-bound:
// 1 float4 stream/thread + store-after-load in a serial T loop leaves ~1 load in
// flight per wave with poor duty cycle. Fix: 2 independent streams per thread +
// register double-buffer prefetch of x[t+1] + nontemporal hints.

typedef float f32x4 __attribute__((ext_vector_type(4)));

__device__ __forceinline__ f32x4 step4(f32x4 h, f32x4 xv, f32x4 wi, f32x4 wh, f32x4 b) {
    f32x4 r;
    float v;
    v = fmaf(wh.x, h.x, fmaf(wi.x, xv.x, b.x)); r.x = (v > 0.f) ? v : 0.01f * v;
    v = fmaf(wh.y, h.y, fmaf(wi.y, xv.y, b.y)); r.y = (v > 0.f) ? v : 0.01f * v;
    v = fmaf(wh.z, h.z, fmaf(wi.z, xv.z, b.z)); r.z = (v > 0.f) ? v : 0.01f * v;
    v = fmaf(wh.w, h.w, fmaf(wi.w, xv.w, b.w)); r.w = (v > 0.f) ? v : 0.01f * v;
    return r;
}

// Fast path: 2 float4 streams per thread, x[t+1] prefetched into registers.
__global__ __launch_bounds__(256) void pixel_rnn_kernel2(
    const f32x4* __restrict__ x,      // (T, nvec)
    const f32x4* __restrict__ wih,    // (nvec)
    const f32x4* __restrict__ whh,    // (nvec)
    const f32x4* __restrict__ bhh,    // (nvec)
    f32x4* __restrict__ out,          // (T, nvec)
    int nvec, int T)
{
    const int half = nvec >> 1;                       // vectors per stream
    int tid = blockIdx.x * blockDim.x + threadIdx.x;
    if (tid >= half) return;

    size_t i0 = (size_t)tid;
    size_t i1 = (size_t)tid + (size_t)half;

    // Weights: load once, keep in registers for the whole recurrence.
    f32x4 wi0 = wih[i0], wi1 = wih[i1];
    f32x4 wh0 = whh[i0], wh1 = whh[i1];
    f32x4 b0  = bhh[i0], b1  = bhh[i1];

    f32x4 h0 = (f32x4)0.f, h1 = (f32x4)0.f;

    size_t stride = (size_t)nvec;
    size_t idx0 = i0, idx1 = i1;

    // Prime the register double-buffer with t=0.
    f32x4 xc0 = __builtin_nontemporal_load(&x[idx0]);
    f32x4 xc1 = __builtin_nontemporal_load(&x[idx1]);

#pragma unroll 2
    for (int t = 0; t < T - 1; ++t) {
        // Prefetch t+1 BEFORE consuming t: these loads stay in flight under
        // the FMA chain + stores of step t.
        f32x4 xn0 = __builtin_nontemporal_load(&x[idx0 + stride]);
        f32x4 xn1 = __builtin_nontemporal_load(&x[idx1 + stride]);

        h0 = step4(h0, xc0, wi0, wh0, b0);
        h1 = step4(h1, xc1, wi1, wh1, b1);

        __builtin_nontemporal_store(h0, &out[idx0]);
        __builtin_nontemporal_store(h1, &out[idx1]);

        idx0 += stride;
        idx1 += stride;
        xc0 = xn0;
        xc1 = xn1;
    }

    // Epilogue: last timestep, no prefetch.
    h0 = step4(h0, xc0, wi0, wh0, b0);
    h1 = step4(h1, xc1, wi1, wh1, b1);
    __builtin_nontemporal_store(h0, &out[idx0]);
    __builtin_nontemporal_store(h1, &out[idx1]);
}

// Generic fallback (1 stream/thread) for nvec not divisible by 2 — same math.
__global__ __launch_bounds__(256) void pixel_rnn_kernel1(
    const f32x4* __restrict__ x,
    const f32x4* __restrict__ wih,
    const f32x4* __restrict__ whh,
    const f32x4* __restrict__ bhh,
    f32x4* __restrict__ out,
    int nvec, int T)
{
    int i = blockIdx.x * blockDim.x + threadIdx.x;
    if (i >= nvec) return;

    f32x4 wi = wih[i];
    f32x4 wh = whh[i];
    f32x4 b  = bhh[i];
    f32x4 h  = (f32x4)0.f;

    size_t idx = (size_t)i;
    size_t stride = (size_t)nvec;

#pragma unroll 2
    for (int t = 0; t < T; ++t) {
        f32x4 xv = __builtin_nontemporal_load(&x[idx]);
        h = step4(h, xv, wi, wh, b);
        __builtin_nontemporal_store(h, &out[idx]);
        idx += stride;
    }
}

extern "C" void kernel_launch(void* const* d_in, const int* in_sizes, int n_in,
                              void* d_out, int out_size, void* d_ws, size_t ws_size,
                              hipStream_t stream) {
    const f32x4* x   = (const f32x4*)d_in[0];
    const f32x4* wih = (const f32x4*)d_in[1];
    const f32x4* whh = (const f32x4*)d_in[2];
    const f32x4* bhh = (const f32x4*)d_in[3];
    f32x4* out = (f32x4*)d_out;

    int npix = in_sizes[1];          // Z*H*W = 2,097,152
    int T    = in_sizes[0] / npix;   // 50
    int nvec = npix / 4;             // float4 vectors = 524,288

    int block = 256;
    if ((nvec & 1) == 0) {
        int nthreads = nvec / 2;     // 262,144 -> 1024 blocks, 16 waves/CU
        int grid = (nthreads + block - 1) / block;
        pixel_rnn_kernel2<<<grid, block, 0, stream>>>(x, wih, whh, bhh, out, nvec, T);
    } else {
        int grid = (nvec + block - 1) / block;
        pixel_rnn_kernel1<<<grid, block, 0, stream>>>(x, wih, whh, bhh, out, nvec, T);
    }
}